// Round 8
// baseline (240.074 us; speedup 1.0000x reference)
//
#include <hip/hip_runtime.h>
#include <hip/hip_bf16.h>

// CrissCrossAttention (full spatial attention with w<->k permuted PV):
//   B=4, C=512, H=W=64, C8=64, HW=4096.
// v5: k_out B-operand direct global->VGPR (no LDS staging), A LDS dbuf 32KB,
//     3 blocks/CU, counted vmcnt(12), 2x-unrolled static-reg pipeline.

typedef __bf16 bf16_t;
typedef __bf16 bf16x8 __attribute__((ext_vector_type(8)));
typedef __bf16 bf16x4 __attribute__((ext_vector_type(4)));
typedef float f32x4 __attribute__((ext_vector_type(4)));

#define HW_ 4096
#define CIN 512
#define CQ 64

__device__ __forceinline__ void gload16(const void* g, void* l) {
  __builtin_amdgcn_global_load_lds((const __attribute__((address_space(1))) void*)g,
                                   (__attribute__((address_space(3))) void*)l, 16, 0, 0);
}

// ---------------- weights pack ----------------
__global__ __launch_bounds__(256) void k_wcat(const float* __restrict__ wq,
                                              const float* __restrict__ wk,
                                              const float* __restrict__ wv,
                                              bf16_t* __restrict__ Wcat) {
  int idx = (blockIdx.x * 256 + threadIdx.x) * 4;
  int row = idx >> 9, c = idx & 511;
  const float* src;
  if (row < 64)       src = wq + row * 512 + c;
  else if (row < 128) src = wk + (row - 64) * 512 + c;
  else                src = wv + (row - 128) * 512 + c;
  float4 v = *(const float4*)src;
  bf16x4 o = { (bf16_t)v.x, (bf16_t)v.y, (bf16_t)v.z, (bf16_t)v.w };
  *(bf16x4*)&Wcat[idx] = o;
}

// ---------------- x transpose + bf16 ----------------
__global__ __launch_bounds__(256) void k_prep(const float* __restrict__ x, bf16_t* __restrict__ xT) {
  __shared__ float tile[64][65];
  const int b = blockIdx.z;
  const int p0 = blockIdx.x * 64, c0 = blockIdx.y * 64;
  const float* xb = x + (size_t)b * CIN * HW_;
  bf16_t* xTb = xT + (size_t)b * HW_ * CIN;
  const int tid = threadIdx.x;
  const int r = tid >> 4, q = tid & 15;
#pragma unroll
  for (int i = 0; i < 4; ++i) {
    int lr = r + 16 * i;
    float4 v = *(const float4*)&xb[(size_t)(c0 + lr) * HW_ + p0 + q * 4];
    tile[lr][q * 4 + 0] = v.x; tile[lr][q * 4 + 1] = v.y;
    tile[lr][q * 4 + 2] = v.z; tile[lr][q * 4 + 3] = v.w;
  }
  __syncthreads();
#pragma unroll
  for (int i = 0; i < 4; ++i) {
    int pr = r + 16 * i;
    bf16x4 o;
    o[0] = (bf16_t)tile[q * 4 + 0][pr];
    o[1] = (bf16_t)tile[q * 4 + 1][pr];
    o[2] = (bf16_t)tile[q * 4 + 2][pr];
    o[3] = (bf16_t)tile[q * 4 + 3][pr];
    *(bf16x4*)&xTb[(size_t)(p0 + pr) * CIN + c0 + q * 4] = o;
  }
}

// ---------------- q/k projection GEMM (Wcat rows 0..127) ----------------
__global__ __launch_bounds__(256) void k_projqk(const bf16_t* __restrict__ Wcat,
                                                const bf16_t* __restrict__ xT,
                                                const float* __restrict__ bq,
                                                const float* __restrict__ bk,
                                                bf16_t* __restrict__ qfT,
                                                bf16_t* __restrict__ kfT) {
  __shared__ bf16_t As[128][64];
  __shared__ bf16_t Bs[128][64];
  const int b = blockIdx.z;
  const int n0 = blockIdx.x * 128;
  const char* Wb = (const char*)Wcat;
  const char* Xb = (const char*)(xT + (size_t)b * HW_ * CIN);
  const int tid = threadIdx.x, wv_ = tid >> 6, lane = tid & 63;
  const int wm = wv_ >> 1, wn = wv_ & 1;
  const int g = lane >> 4, cc = lane & 15;
  f32x4 acc[4][4]{};
  for (int ks = 0; ks < 512; ks += 64) {
    if (ks) __syncthreads();
#pragma unroll
    for (int i = 0; i < 4; ++i) {
      int ch = wv_ * 4 + i;
      int rr = ch * 8 + (lane >> 3);
      int sl = (lane & 7) ^ (rr & 7);
      gload16(Wb + (size_t)rr * 1024 + ks * 2 + sl * 16, (char*)As + ch * 1024);
      gload16(Xb + (size_t)(n0 + rr) * 1024 + ks * 2 + sl * 16, (char*)Bs + ch * 1024);
    }
    __syncthreads();
#pragma unroll
    for (int k2 = 0; k2 < 2; ++k2) {
      bf16x8 a[4], bb[4];
#pragma unroll
      for (int f = 0; f < 4; ++f)
        a[f] = *(const bf16x8*)((char*)As + (wm * 64 + f * 16 + cc) * 128 + (((k2 * 4 + g) ^ (cc & 7)) * 16));
#pragma unroll
      for (int f = 0; f < 4; ++f)
        bb[f] = *(const bf16x8*)((char*)Bs + (wn * 64 + f * 16 + cc) * 128 + (((k2 * 4 + g) ^ (cc & 7)) * 16));
#pragma unroll
      for (int fm = 0; fm < 4; ++fm)
#pragma unroll
        for (int fn = 0; fn < 4; ++fn)
          acc[fm][fn] = __builtin_amdgcn_mfma_f32_16x16x32_bf16(a[fm], bb[fn], acc[fm][fn], 0, 0, 0);
    }
  }
  bf16_t* qb = qfT + (size_t)b * HW_ * CQ;
  bf16_t* kb = kfT + (size_t)b * HW_ * CQ;
#pragma unroll
  for (int fm = 0; fm < 4; ++fm) {
#pragma unroll
    for (int j = 0; j < 4; ++j) {
      int m = wm * 64 + fm * 16 + g * 4 + j;
      float bias = (m < 64) ? bq[m] : bk[m - 64];
#pragma unroll
      for (int fn = 0; fn < 4; ++fn) {
        int n = n0 + wn * 64 + fn * 16 + cc;
        float val = acc[fm][fn][j] + bias;
        if (m < 64) qb[(size_t)n * CQ + m] = (bf16_t)val;
        else        kb[(size_t)n * CQ + (m - 64)] = (bf16_t)val;
      }
    }
  }
}

// ---------------- V projection GEMM (Wcat rows 128..639, permuted pixels) ----------------
__global__ __launch_bounds__(256) void k_projv(const bf16_t* __restrict__ Wcat,
                                               const bf16_t* __restrict__ xT,
                                               const float* __restrict__ bv,
                                               bf16_t* __restrict__ Vp2) {
  __shared__ bf16_t As[128][64];
  __shared__ bf16_t Bs[128][64];
  const int b = blockIdx.z;
  const int n0 = blockIdx.x * 128, m0 = blockIdx.y * 128;
  const char* Wb = (const char*)Wcat;
  const char* Xb = (const char*)(xT + (size_t)b * HW_ * CIN);
  const int tid = threadIdx.x, wv_ = tid >> 6, lane = tid & 63;
  const int wm = wv_ >> 1, wn = wv_ & 1;
  const int g = lane >> 4, cc = lane & 15;
  f32x4 acc[4][4]{};
  for (int ks = 0; ks < 512; ks += 64) {
    if (ks) __syncthreads();
#pragma unroll
    for (int i = 0; i < 4; ++i) {
      int ch = wv_ * 4 + i;
      int rr = ch * 8 + (lane >> 3);
      int sl = (lane & 7) ^ (rr & 7);
      int pix = (rr & 63) * 64 + (blockIdx.x * 2) + (rr >> 6);  // perm(n0+rr)
      gload16(Wb + (size_t)(128 + m0 + rr) * 1024 + ks * 2 + sl * 16, (char*)As + ch * 1024);
      gload16(Xb + (size_t)pix * 1024 + ks * 2 + sl * 16, (char*)Bs + ch * 1024);
    }
    __syncthreads();
#pragma unroll
    for (int k2 = 0; k2 < 2; ++k2) {
      bf16x8 a[4], bb[4];
#pragma unroll
      for (int f = 0; f < 4; ++f)
        a[f] = *(const bf16x8*)((char*)As + (wm * 64 + f * 16 + cc) * 128 + (((k2 * 4 + g) ^ (cc & 7)) * 16));
#pragma unroll
      for (int f = 0; f < 4; ++f)
        bb[f] = *(const bf16x8*)((char*)Bs + (wn * 64 + f * 16 + cc) * 128 + (((k2 * 4 + g) ^ (cc & 7)) * 16));
#pragma unroll
      for (int fm = 0; fm < 4; ++fm)
#pragma unroll
        for (int fn = 0; fn < 4; ++fn)
          acc[fm][fn] = __builtin_amdgcn_mfma_f32_16x16x32_bf16(a[fm], bb[fn], acc[fm][fn], 0, 0, 0);
    }
  }
  bf16_t* Vb = Vp2 + (size_t)b * CIN * HW_;
#pragma unroll
  for (int fm = 0; fm < 4; ++fm) {
#pragma unroll
    for (int j = 0; j < 4; ++j) {
      int m = m0 + wm * 64 + fm * 16 + g * 4 + j;
      float bias = bv[m];
#pragma unroll
      for (int fn = 0; fn < 4; ++fn) {
        int n = n0 + wn * 64 + fn * 16 + cc;
        Vb[(size_t)m * HW_ + n] = (bf16_t)(acc[fm][fn][j] + bias);
      }
    }
  }
}

// ---------------- energy + softmax(v) -> Pt[b][w][k][v][h] ----------------
__global__ __launch_bounds__(256) void k_energy(const bf16_t* __restrict__ qfT,
                                                const bf16_t* __restrict__ kfT,
                                                bf16_t* __restrict__ Pt, int zbase) {
  __shared__ bf16_t As[128][64];
  __shared__ bf16_t Bs[64][64];
  const int b = zbase + blockIdx.z;
  const int w0 = blockIdx.x * 2, ky = blockIdx.y;
  const char* qb = (const char*)(qfT + (size_t)b * HW_ * CQ);
  const char* kb = (const char*)(kfT + (size_t)b * HW_ * CQ);
  bf16_t* Ptb = Pt + (size_t)blockIdx.z * 16777216;
  const int tid = threadIdx.x, wv_ = tid >> 6, lane = tid & 63;
  const int g = lane >> 4, cc = lane & 15;
  f32x4 acc[2][4]{};
#pragma unroll
  for (int i = 0; i < 4; ++i) {
    int ch = wv_ * 4 + i;
    int rr = ch * 8 + (lane >> 3);
    int sl = (lane & 7) ^ (rr & 7);
    int pix = (rr & 63) * 64 + w0 + (rr >> 6);
    gload16(qb + (size_t)pix * 128 + sl * 16, (char*)As + ch * 1024);
  }
#pragma unroll
  for (int i = 0; i < 2; ++i) {
    int ch = wv_ * 2 + i;
    int rr = ch * 8 + (lane >> 3);
    int sl = (lane & 7) ^ (rr & 7);
    gload16(kb + (size_t)(ky * 64 + rr) * 128 + sl * 16, (char*)Bs + ch * 1024);
  }
  __syncthreads();
#pragma unroll
  for (int k2 = 0; k2 < 2; ++k2) {
    bf16x8 a[2], bb[4];
#pragma unroll
    for (int f = 0; f < 2; ++f)
      a[f] = *(const bf16x8*)((char*)As + (wv_ * 32 + f * 16 + cc) * 128 + (((k2 * 4 + g) ^ (cc & 7)) * 16));
#pragma unroll
    for (int f = 0; f < 4; ++f)
      bb[f] = *(const bf16x8*)((char*)Bs + (f * 16 + cc) * 128 + (((k2 * 4 + g) ^ (cc & 7)) * 16));
#pragma unroll
    for (int fm = 0; fm < 2; ++fm)
#pragma unroll
      for (int fn = 0; fn < 4; ++fn)
        acc[fm][fn] = __builtin_amdgcn_mfma_f32_16x16x32_bf16(a[fm], bb[fn], acc[fm][fn], 0, 0, 0);
  }
  const int w = w0 + (wv_ >> 1);
#pragma unroll
  for (int fm = 0; fm < 2; ++fm) {
    float e[4][4], invj[4];
#pragma unroll
    for (int j = 0; j < 4; ++j) {
      float mx = fmaxf(fmaxf(acc[fm][0][j], acc[fm][1][j]), fmaxf(acc[fm][2][j], acc[fm][3][j]));
#pragma unroll
      for (int d = 1; d < 16; d <<= 1) mx = fmaxf(mx, __shfl_xor(mx, d, 64));
      float s = 0.f;
#pragma unroll
      for (int fn = 0; fn < 4; ++fn) { e[fn][j] = __expf(acc[fm][fn][j] - mx); s += e[fn][j]; }
#pragma unroll
      for (int d = 1; d < 16; d <<= 1) s += __shfl_xor(s, d, 64);
      invj[j] = __builtin_amdgcn_rcpf(s);
    }
    int h0 = (wv_ & 1) * 32 + fm * 16 + g * 4;
#pragma unroll
    for (int fn = 0; fn < 4; ++fn) {
      int v = fn * 16 + cc;
      bf16x4 pk = { (bf16_t)(e[fn][0] * invj[0]), (bf16_t)(e[fn][1] * invj[1]),
                    (bf16_t)(e[fn][2] * invj[2]), (bf16_t)(e[fn][3] * invj[3]) };
      *(bf16x4*)&Ptb[(((size_t)w * 64 + ky) * 64 + v) * 64 + h0] = pk;
    }
  }
}

// ---------------- out GEMM v5 + epilogue ----------------
// Block 128c x (2w x 64v), waves 2x2. A (Vp2) via XOR-swizzled gload_lds dbuf;
// B (Pt) DIRECT global->VGPR bf16x8, prefetch distance 1; vmcnt(12) counted.
#define LOADB(dst, base) do {                              \
    dst[0] = *(const bf16x8*)((base));                     \
    dst[1] = *(const bf16x8*)((base) + 64);                \
    dst[2] = *(const bf16x8*)((base) + 2048);              \
    dst[3] = *(const bf16x8*)((base) + 2112);              \
    dst[4] = *(const bf16x8*)((base) + 4096);              \
    dst[5] = *(const bf16x8*)((base) + 4160);              \
    dst[6] = *(const bf16x8*)((base) + 6144);              \
    dst[7] = *(const bf16x8*)((base) + 6208);              \
  } while (0)

#define COMPUTE(lbase, breg) do {                                                                  \
    _Pragma("unroll")                                                                              \
    for (int k2 = 0; k2 < 2; ++k2) {                                                               \
      bf16x8 afr[4];                                                                               \
      _Pragma("unroll")                                                                            \
      for (int fm = 0; fm < 4; ++fm) afr[fm] = *(const bf16x8*)((lbase) + aoff[k2][fm]);           \
      _Pragma("unroll")                                                                            \
      for (int fm = 0; fm < 4; ++fm) {                                                             \
        acc[fm][0] = __builtin_amdgcn_mfma_f32_16x16x32_bf16(afr[fm], breg[k2],     acc[fm][0], 0, 0, 0); \
        acc[fm][1] = __builtin_amdgcn_mfma_f32_16x16x32_bf16(afr[fm], breg[2 + k2], acc[fm][1], 0, 0, 0); \
        acc[fm][2] = __builtin_amdgcn_mfma_f32_16x16x32_bf16(afr[fm], breg[4 + k2], acc[fm][2], 0, 0, 0); \
        acc[fm][3] = __builtin_amdgcn_mfma_f32_16x16x32_bf16(afr[fm], breg[6 + k2], acc[fm][3], 0, 0, 0); \
      }                                                                                            \
    }                                                                                              \
  } while (0)

__global__ __launch_bounds__(256, 3) void k_out(const bf16_t* __restrict__ Vp2,
                                                const bf16_t* __restrict__ Pt,
                                                const float* __restrict__ x,
                                                const float* __restrict__ gamma,
                                                float* __restrict__ outp, int zbase) {
  __shared__ char As2[32768];  // 2 x 16KB A double-buffer
  const int b = zbase + blockIdx.z;
  const int c0 = blockIdx.x * 128, w0 = blockIdx.y * 2;
  const char* Vb = (const char*)(Vp2 + (size_t)b * CIN * HW_);
  const char* Pb = (const char*)(Pt + (size_t)blockIdx.z * 16777216);
  const int tid = threadIdx.x, wv_ = tid >> 6, lane = tid & 63;
  const int wm = wv_ >> 1, wn = wv_ & 1;
  const int g = lane >> 4, cc = lane & 15;

  // A staging sources (XOR-swizzled global side), 4 gload16 per wave per step.
  const char* aSb[4];
  char* aD0[4]; char* aD1[4];
#pragma unroll
  for (int r = 0; r < 4; ++r) {
    int L = (r * 4 + wv_) * 64 + lane;
    int arow = L >> 3, asl = (L & 7) ^ (arow & 7);
    aSb[r] = Vb + (size_t)(c0 + arow) * 8192 + asl * 16;
    aD0[r] = As2 + (r * 4 + wv_) * 1024;
    aD1[r] = aD0[r] + 16384;
  }
  int aoff[2][4];
#pragma unroll
  for (int k2 = 0; k2 < 2; ++k2)
#pragma unroll
    for (int fm = 0; fm < 4; ++fm)
      aoff[k2][fm] = (wm * 64 + fm * 16 + cc) * 128 + (((k2 * 4 + g) ^ (cc & 7)) * 16);

  // B direct base: frag (fn,k2) at base + fn*2048 + k2*64; step stride 8192.
  const char* bB = Pb + (size_t)(w0 + wn) * 524288 + (size_t)cc * 128 + g * 16;

  f32x4 acc[4][4]{};
  bf16x8 b0[8], b1[8];
  // prologue: stage A(0) -> buf0; load B(0) regs
#pragma unroll
  for (int r = 0; r < 4; ++r) gload16(aSb[r], aD0[r]);
  LOADB(b0, bB);

  for (int s2 = 0; s2 < 32; ++s2) {
    // ---- even step s=2*s2: compute buf0/b0, prefetch s+1 -> buf1/b1 ----
    {
#pragma unroll
      for (int r = 0; r < 4; ++r) gload16(aSb[r] + (size_t)(2 * s2 + 1) * 128, aD1[r]);
      const char* q = bB + 8192;
      LOADB(b1, q);
      asm volatile("s_waitcnt vmcnt(12)" ::: "memory");
      __builtin_amdgcn_s_barrier();
      COMPUTE(As2, b0);
      asm volatile("s_waitcnt lgkmcnt(0)" ::: "memory");
      __builtin_amdgcn_s_barrier();
    }
    // ---- odd step s=2*s2+1: compute buf1/b1, prefetch s+2 -> buf0/b0 ----
    {
      if (s2 < 31) {
#pragma unroll
        for (int r = 0; r < 4; ++r) gload16(aSb[r] + (size_t)(2 * s2 + 2) * 128, aD0[r]);
        const char* q = bB + 16384;
        LOADB(b0, q);
        asm volatile("s_waitcnt vmcnt(12)" ::: "memory");
      } else {
        asm volatile("s_waitcnt vmcnt(0)" ::: "memory");
      }
      __builtin_amdgcn_s_barrier();
      COMPUTE(As2 + 16384, b1);
      asm volatile("s_waitcnt lgkmcnt(0)" ::: "memory");
      __builtin_amdgcn_s_barrier();
      bB += 16384;
    }
  }
  const float gmm = gamma[0];
  const float* xb = x + (size_t)b * CIN * HW_;
  float* ob = outp + (size_t)b * CIN * HW_;
  const int w = w0 + wn;
#pragma unroll
  for (int fm = 0; fm < 4; ++fm) {
#pragma unroll
    for (int jj = 0; jj < 4; ++jj) {
      int c = c0 + wm * 64 + fm * 16 + g * 4 + jj;
#pragma unroll
      for (int fn = 0; fn < 4; ++fn) {
        int n = w * 64 + fn * 16 + cc;
        size_t idx = (size_t)c * HW_ + n;
        ob[idx] = gmm * acc[fm][fn][jj] + xb[idx];
      }
    }
  }
}

extern "C" void kernel_launch(void* const* d_in, const int* in_sizes, int n_in,
                              void* d_out, int out_size, void* d_ws, size_t ws_size,
                              hipStream_t stream) {
  const float* x  = (const float*)d_in[0];
  const float* wq = (const float*)d_in[1];
  const float* bq = (const float*)d_in[2];
  const float* wk = (const float*)d_in[3];
  const float* bk = (const float*)d_in[4];
  const float* wv = (const float*)d_in[5];
  const float* bv = (const float*)d_in[6];
  const float* gamma = (const float*)d_in[7];
  float* outp = (float*)d_out;
  char* ws = (char*)d_ws;
  size_t off = 0;
  bf16_t* xT   = (bf16_t*)(ws + off); off += (size_t)4 * HW_ * CIN * 2;   // 16 MB
  bf16_t* Wcat = (bf16_t*)(ws + off); off += (size_t)640 * CIN * 2;       // 640 KB
  bf16_t* qfT  = (bf16_t*)(ws + off); off += (size_t)4 * HW_ * CQ * 2;    // 2 MB
  bf16_t* kfT  = (bf16_t*)(ws + off); off += (size_t)4 * HW_ * CQ * 2;    // 2 MB
  bf16_t* Vp2  = (bf16_t*)(ws + off); off += (size_t)4 * CIN * HW_ * 2;   // 16 MB
  bf16_t* Pt   = (bf16_t*)(ws + off);
  const size_t pbytes = (size_t)HW_ * HW_ * 2;                            // 32 MB / batch
  const bool full = (ws_size >= off + 4 * pbytes);

  k_wcat<<<dim3(320), dim3(256), 0, stream>>>(wq, wk, wv, Wcat);
  k_prep<<<dim3(64, 8, 4), dim3(256), 0, stream>>>(x, xT);
  k_projqk<<<dim3(32, 1, 4), dim3(256), 0, stream>>>(Wcat, xT, bq, bk, qfT, kfT);
  k_projv<<<dim3(32, 4, 4), dim3(256), 0, stream>>>(Wcat, xT, bv, Vp2);
  if (full) {
    k_energy<<<dim3(32, 64, 4), dim3(256), 0, stream>>>(qfT, kfT, Pt, 0);
    k_out<<<dim3(4, 32, 4), dim3(256), 0, stream>>>(Vp2, Pt, x, gamma, outp, 0);
  } else {
    for (int b = 0; b < 4; ++b) {
      k_energy<<<dim3(32, 64, 1), dim3(256), 0, stream>>>(qfT, kfT, Pt, b);
      k_out<<<dim3(4, 32, 1), dim3(256), 0, stream>>>(Vp2, Pt, x, gamma, outp, b);
    }
  }
}

// Round 9
// 232.270 us; speedup vs baseline: 1.0336x; 1.0336x over previous
//
#include <hip/hip_runtime.h>
#include <hip/hip_bf16.h>

// CrissCrossAttention (full spatial attention with w<->k permuted PV):
//   B=4, C=512, H=W=64, C8=64, HW=4096.
// v6: k_out B-operand via inline-asm global_load_dwordx4 -> VGPR (compiler can't
//     insert conservative waits; manual vmcnt(12) + sched_barrier per rule #18),
//     A via XOR-swizzled gload_lds dbuf (32KB), bijective XCD swizzle for B-panel
//     L2 locality. Rest of pipeline unchanged (validated).

typedef __bf16 bf16_t;
typedef __bf16 bf16x8 __attribute__((ext_vector_type(8)));
typedef __bf16 bf16x4 __attribute__((ext_vector_type(4)));
typedef float f32x4 __attribute__((ext_vector_type(4)));

#define HW_ 4096
#define CIN 512
#define CQ 64

__device__ __forceinline__ void gload16(const void* g, void* l) {
  __builtin_amdgcn_global_load_lds((const __attribute__((address_space(1))) void*)g,
                                   (__attribute__((address_space(3))) void*)l, 16, 0, 0);
}

// ---------------- weights pack ----------------
__global__ __launch_bounds__(256) void k_wcat(const float* __restrict__ wq,
                                              const float* __restrict__ wk,
                                              const float* __restrict__ wv,
                                              bf16_t* __restrict__ Wcat) {
  int idx = (blockIdx.x * 256 + threadIdx.x) * 4;
  int row = idx >> 9, c = idx & 511;
  const float* src;
  if (row < 64)       src = wq + row * 512 + c;
  else if (row < 128) src = wk + (row - 64) * 512 + c;
  else                src = wv + (row - 128) * 512 + c;
  float4 v = *(const float4*)src;
  bf16x4 o = { (bf16_t)v.x, (bf16_t)v.y, (bf16_t)v.z, (bf16_t)v.w };
  *(bf16x4*)&Wcat[idx] = o;
}

// ---------------- x transpose + bf16 ----------------
__global__ __launch_bounds__(256) void k_prep(const float* __restrict__ x, bf16_t* __restrict__ xT) {
  __shared__ float tile[64][65];
  const int b = blockIdx.z;
  const int p0 = blockIdx.x * 64, c0 = blockIdx.y * 64;
  const float* xb = x + (size_t)b * CIN * HW_;
  bf16_t* xTb = xT + (size_t)b * HW_ * CIN;
  const int tid = threadIdx.x;
  const int r = tid >> 4, q = tid & 15;
#pragma unroll
  for (int i = 0; i < 4; ++i) {
    int lr = r + 16 * i;
    float4 v = *(const float4*)&xb[(size_t)(c0 + lr) * HW_ + p0 + q * 4];
    tile[lr][q * 4 + 0] = v.x; tile[lr][q * 4 + 1] = v.y;
    tile[lr][q * 4 + 2] = v.z; tile[lr][q * 4 + 3] = v.w;
  }
  __syncthreads();
#pragma unroll
  for (int i = 0; i < 4; ++i) {
    int pr = r + 16 * i;
    bf16x4 o;
    o[0] = (bf16_t)tile[q * 4 + 0][pr];
    o[1] = (bf16_t)tile[q * 4 + 1][pr];
    o[2] = (bf16_t)tile[q * 4 + 2][pr];
    o[3] = (bf16_t)tile[q * 4 + 3][pr];
    *(bf16x4*)&xTb[(size_t)(p0 + pr) * CIN + c0 + q * 4] = o;
  }
}

// ---------------- q/k projection GEMM (Wcat rows 0..127) ----------------
__global__ __launch_bounds__(256) void k_projqk(const bf16_t* __restrict__ Wcat,
                                                const bf16_t* __restrict__ xT,
                                                const float* __restrict__ bq,
                                                const float* __restrict__ bk,
                                                bf16_t* __restrict__ qfT,
                                                bf16_t* __restrict__ kfT) {
  __shared__ bf16_t As[128][64];
  __shared__ bf16_t Bs[128][64];
  const int b = blockIdx.z;
  const int n0 = blockIdx.x * 128;
  const char* Wb = (const char*)Wcat;
  const char* Xb = (const char*)(xT + (size_t)b * HW_ * CIN);
  const int tid = threadIdx.x, wv_ = tid >> 6, lane = tid & 63;
  const int wm = wv_ >> 1, wn = wv_ & 1;
  const int g = lane >> 4, cc = lane & 15;
  f32x4 acc[4][4]{};
  for (int ks = 0; ks < 512; ks += 64) {
    if (ks) __syncthreads();
#pragma unroll
    for (int i = 0; i < 4; ++i) {
      int ch = wv_ * 4 + i;
      int rr = ch * 8 + (lane >> 3);
      int sl = (lane & 7) ^ (rr & 7);
      gload16(Wb + (size_t)rr * 1024 + ks * 2 + sl * 16, (char*)As + ch * 1024);
      gload16(Xb + (size_t)(n0 + rr) * 1024 + ks * 2 + sl * 16, (char*)Bs + ch * 1024);
    }
    __syncthreads();
#pragma unroll
    for (int k2 = 0; k2 < 2; ++k2) {
      bf16x8 a[4], bb[4];
#pragma unroll
      for (int f = 0; f < 4; ++f)
        a[f] = *(const bf16x8*)((char*)As + (wm * 64 + f * 16 + cc) * 128 + (((k2 * 4 + g) ^ (cc & 7)) * 16));
#pragma unroll
      for (int f = 0; f < 4; ++f)
        bb[f] = *(const bf16x8*)((char*)Bs + (wn * 64 + f * 16 + cc) * 128 + (((k2 * 4 + g) ^ (cc & 7)) * 16));
#pragma unroll
      for (int fm = 0; fm < 4; ++fm)
#pragma unroll
        for (int fn = 0; fn < 4; ++fn)
          acc[fm][fn] = __builtin_amdgcn_mfma_f32_16x16x32_bf16(a[fm], bb[fn], acc[fm][fn], 0, 0, 0);
    }
  }
  bf16_t* qb = qfT + (size_t)b * HW_ * CQ;
  bf16_t* kb = kfT + (size_t)b * HW_ * CQ;
#pragma unroll
  for (int fm = 0; fm < 4; ++fm) {
#pragma unroll
    for (int j = 0; j < 4; ++j) {
      int m = wm * 64 + fm * 16 + g * 4 + j;
      float bias = (m < 64) ? bq[m] : bk[m - 64];
#pragma unroll
      for (int fn = 0; fn < 4; ++fn) {
        int n = n0 + wn * 64 + fn * 16 + cc;
        float val = acc[fm][fn][j] + bias;
        if (m < 64) qb[(size_t)n * CQ + m] = (bf16_t)val;
        else        kb[(size_t)n * CQ + (m - 64)] = (bf16_t)val;
      }
    }
  }
}

// ---------------- V projection GEMM (Wcat rows 128..639, permuted pixels) ----------------
__global__ __launch_bounds__(256) void k_projv(const bf16_t* __restrict__ Wcat,
                                               const bf16_t* __restrict__ xT,
                                               const float* __restrict__ bv,
                                               bf16_t* __restrict__ Vp2) {
  __shared__ bf16_t As[128][64];
  __shared__ bf16_t Bs[128][64];
  const int b = blockIdx.z;
  const int n0 = blockIdx.x * 128, m0 = blockIdx.y * 128;
  const char* Wb = (const char*)Wcat;
  const char* Xb = (const char*)(xT + (size_t)b * HW_ * CIN);
  const int tid = threadIdx.x, wv_ = tid >> 6, lane = tid & 63;
  const int wm = wv_ >> 1, wn = wv_ & 1;
  const int g = lane >> 4, cc = lane & 15;
  f32x4 acc[4][4]{};
  for (int ks = 0; ks < 512; ks += 64) {
    if (ks) __syncthreads();
#pragma unroll
    for (int i = 0; i < 4; ++i) {
      int ch = wv_ * 4 + i;
      int rr = ch * 8 + (lane >> 3);
      int sl = (lane & 7) ^ (rr & 7);
      int pix = (rr & 63) * 64 + (blockIdx.x * 2) + (rr >> 6);  // perm(n0+rr)
      gload16(Wb + (size_t)(128 + m0 + rr) * 1024 + ks * 2 + sl * 16, (char*)As + ch * 1024);
      gload16(Xb + (size_t)pix * 1024 + ks * 2 + sl * 16, (char*)Bs + ch * 1024);
    }
    __syncthreads();
#pragma unroll
    for (int k2 = 0; k2 < 2; ++k2) {
      bf16x8 a[4], bb[4];
#pragma unroll
      for (int f = 0; f < 4; ++f)
        a[f] = *(const bf16x8*)((char*)As + (wm * 64 + f * 16 + cc) * 128 + (((k2 * 4 + g) ^ (cc & 7)) * 16));
#pragma unroll
      for (int f = 0; f < 4; ++f)
        bb[f] = *(const bf16x8*)((char*)Bs + (wn * 64 + f * 16 + cc) * 128 + (((k2 * 4 + g) ^ (cc & 7)) * 16));
#pragma unroll
      for (int fm = 0; fm < 4; ++fm)
#pragma unroll
        for (int fn = 0; fn < 4; ++fn)
          acc[fm][fn] = __builtin_amdgcn_mfma_f32_16x16x32_bf16(a[fm], bb[fn], acc[fm][fn], 0, 0, 0);
    }
  }
  bf16_t* Vb = Vp2 + (size_t)b * CIN * HW_;
#pragma unroll
  for (int fm = 0; fm < 4; ++fm) {
#pragma unroll
    for (int j = 0; j < 4; ++j) {
      int m = m0 + wm * 64 + fm * 16 + g * 4 + j;
      float bias = bv[m];
#pragma unroll
      for (int fn = 0; fn < 4; ++fn) {
        int n = n0 + wn * 64 + fn * 16 + cc;
        Vb[(size_t)m * HW_ + n] = (bf16_t)(acc[fm][fn][j] + bias);
      }
    }
  }
}

// ---------------- energy + softmax(v) -> Pt[b][w][k][v][h] ----------------
__global__ __launch_bounds__(256) void k_energy(const bf16_t* __restrict__ qfT,
                                                const bf16_t* __restrict__ kfT,
                                                bf16_t* __restrict__ Pt, int zbase) {
  __shared__ bf16_t As[128][64];
  __shared__ bf16_t Bs[64][64];
  const int b = zbase + blockIdx.z;
  const int w0 = blockIdx.x * 2, ky = blockIdx.y;
  const char* qb = (const char*)(qfT + (size_t)b * HW_ * CQ);
  const char* kb = (const char*)(kfT + (size_t)b * HW_ * CQ);
  bf16_t* Ptb = Pt + (size_t)blockIdx.z * 16777216;
  const int tid = threadIdx.x, wv_ = tid >> 6, lane = tid & 63;
  const int g = lane >> 4, cc = lane & 15;
  f32x4 acc[2][4]{};
#pragma unroll
  for (int i = 0; i < 4; ++i) {
    int ch = wv_ * 4 + i;
    int rr = ch * 8 + (lane >> 3);
    int sl = (lane & 7) ^ (rr & 7);
    int pix = (rr & 63) * 64 + w0 + (rr >> 6);
    gload16(qb + (size_t)pix * 128 + sl * 16, (char*)As + ch * 1024);
  }
#pragma unroll
  for (int i = 0; i < 2; ++i) {
    int ch = wv_ * 2 + i;
    int rr = ch * 8 + (lane >> 3);
    int sl = (lane & 7) ^ (rr & 7);
    gload16(kb + (size_t)(ky * 64 + rr) * 128 + sl * 16, (char*)Bs + ch * 1024);
  }
  __syncthreads();
#pragma unroll
  for (int k2 = 0; k2 < 2; ++k2) {
    bf16x8 a[2], bb[4];
#pragma unroll
    for (int f = 0; f < 2; ++f)
      a[f] = *(const bf16x8*)((char*)As + (wv_ * 32 + f * 16 + cc) * 128 + (((k2 * 4 + g) ^ (cc & 7)) * 16));
#pragma unroll
    for (int f = 0; f < 4; ++f)
      bb[f] = *(const bf16x8*)((char*)Bs + (f * 16 + cc) * 128 + (((k2 * 4 + g) ^ (cc & 7)) * 16));
#pragma unroll
    for (int fm = 0; fm < 2; ++fm)
#pragma unroll
      for (int fn = 0; fn < 4; ++fn)
        acc[fm][fn] = __builtin_amdgcn_mfma_f32_16x16x32_bf16(a[fm], bb[fn], acc[fm][fn], 0, 0, 0);
  }
  const int w = w0 + (wv_ >> 1);
#pragma unroll
  for (int fm = 0; fm < 2; ++fm) {
    float e[4][4], invj[4];
#pragma unroll
    for (int j = 0; j < 4; ++j) {
      float mx = fmaxf(fmaxf(acc[fm][0][j], acc[fm][1][j]), fmaxf(acc[fm][2][j], acc[fm][3][j]));
#pragma unroll
      for (int d = 1; d < 16; d <<= 1) mx = fmaxf(mx, __shfl_xor(mx, d, 64));
      float s = 0.f;
#pragma unroll
      for (int fn = 0; fn < 4; ++fn) { e[fn][j] = __expf(acc[fm][fn][j] - mx); s += e[fn][j]; }
#pragma unroll
      for (int d = 1; d < 16; d <<= 1) s += __shfl_xor(s, d, 64);
      invj[j] = __builtin_amdgcn_rcpf(s);
    }
    int h0 = (wv_ & 1) * 32 + fm * 16 + g * 4;
#pragma unroll
    for (int fn = 0; fn < 4; ++fn) {
      int v = fn * 16 + cc;
      bf16x4 pk = { (bf16_t)(e[fn][0] * invj[0]), (bf16_t)(e[fn][1] * invj[1]),
                    (bf16_t)(e[fn][2] * invj[2]), (bf16_t)(e[fn][3] * invj[3]) };
      *(bf16x4*)&Ptb[(((size_t)w * 64 + ky) * 64 + v) * 64 + h0] = pk;
    }
  }
}

// ---------------- out GEMM v6 + epilogue ----------------
// Block 128c x (2w x 64v), waves 2x2. A (Vp2): XOR-swizzled gload_lds dbuf 32KB.
// B (Pt): asm global_load_dwordx4 -> VGPR, depth-1 prefetch, manual vmcnt(12).
#define LOADB_ASM(dst, base) do {                                                            \
    const char* _p0 = (base);                                                                \
    const char* _p1 = (base) + 4096;                                                         \
    asm volatile("global_load_dwordx4 %0, %1, off"             : "=v"(dst[0]) : "v"(_p0));   \
    asm volatile("global_load_dwordx4 %0, %1, off offset:64"   : "=v"(dst[1]) : "v"(_p0));   \
    asm volatile("global_load_dwordx4 %0, %1, off offset:2048" : "=v"(dst[2]) : "v"(_p0));   \
    asm volatile("global_load_dwordx4 %0, %1, off offset:2112" : "=v"(dst[3]) : "v"(_p0));   \
    asm volatile("global_load_dwordx4 %0, %1, off"             : "=v"(dst[4]) : "v"(_p1));   \
    asm volatile("global_load_dwordx4 %0, %1, off offset:64"   : "=v"(dst[5]) : "v"(_p1));   \
    asm volatile("global_load_dwordx4 %0, %1, off offset:2048" : "=v"(dst[6]) : "v"(_p1));   \
    asm volatile("global_load_dwordx4 %0, %1, off offset:2112" : "=v"(dst[7]) : "v"(_p1));   \
  } while (0)

#define COMPUTE(lbase, breg) do {                                                                  \
    _Pragma("unroll")                                                                              \
    for (int k2 = 0; k2 < 2; ++k2) {                                                               \
      bf16x8 afr[4];                                                                               \
      _Pragma("unroll")                                                                            \
      for (int fm = 0; fm < 4; ++fm) afr[fm] = *(const bf16x8*)((lbase) + aoff[k2][fm]);           \
      _Pragma("unroll")                                                                            \
      for (int fm = 0; fm < 4; ++fm) {                                                             \
        acc[fm][0] = __builtin_amdgcn_mfma_f32_16x16x32_bf16(afr[fm], breg[k2],     acc[fm][0], 0, 0, 0); \
        acc[fm][1] = __builtin_amdgcn_mfma_f32_16x16x32_bf16(afr[fm], breg[2 + k2], acc[fm][1], 0, 0, 0); \
        acc[fm][2] = __builtin_amdgcn_mfma_f32_16x16x32_bf16(afr[fm], breg[4 + k2], acc[fm][2], 0, 0, 0); \
        acc[fm][3] = __builtin_amdgcn_mfma_f32_16x16x32_bf16(afr[fm], breg[6 + k2], acc[fm][3], 0, 0, 0); \
      }                                                                                            \
    }                                                                                              \
  } while (0)

__global__ __launch_bounds__(256, 3) void k_out(const bf16_t* __restrict__ Vp2,
                                                const bf16_t* __restrict__ Pt,
                                                const float* __restrict__ x,
                                                const float* __restrict__ gamma,
                                                float* __restrict__ outp, int zbase) {
  __shared__ char As2[32768];  // 2 x 16KB A double-buffer
  // Bijective XCD swizzle: co-locate the 4 c-blocks of each w-panel (B L2 reuse).
  const int lin = blockIdx.x + (blockIdx.y << 2) + (blockIdx.z << 7);
  const int nwg8 = (gridDim.z == 4) ? 64 : 16;
  const int rsw = (lin & 7) * nwg8 + (lin >> 3);
  const int c0 = (rsw & 3) * 128;
  const int w0 = ((rsw >> 2) & 31) * 2;
  const int bz = (gridDim.z == 4) ? (rsw >> 7) : 0;
  const int b = zbase + bz;
  const char* Vb = (const char*)(Vp2 + (size_t)b * CIN * HW_);
  const char* Pb = (const char*)(Pt + (size_t)bz * 16777216);
  const int tid = threadIdx.x, wv_ = tid >> 6, lane = tid & 63;
  const int wm = wv_ >> 1, wn = wv_ & 1;
  const int g = lane >> 4, cc = lane & 15;

  const char* aSb[4];
  char* aD0[4]; char* aD1[4];
#pragma unroll
  for (int r = 0; r < 4; ++r) {
    int L = (r * 4 + wv_) * 64 + lane;
    int arow = L >> 3, asl = (L & 7) ^ (arow & 7);
    aSb[r] = Vb + (size_t)(c0 + arow) * 8192 + asl * 16;
    aD0[r] = As2 + (r * 4 + wv_) * 1024;
    aD1[r] = aD0[r] + 16384;
  }
  int aoff[2][4];
#pragma unroll
  for (int k2 = 0; k2 < 2; ++k2)
#pragma unroll
    for (int fm = 0; fm < 4; ++fm)
      aoff[k2][fm] = (wm * 64 + fm * 16 + cc) * 128 + (((k2 * 4 + g) ^ (cc & 7)) * 16);

  // B direct base: frag (fn,k2) at base + fn*2048 + k2*64; step stride 8192.
  const char* bB = Pb + (size_t)(w0 + wn) * 524288 + (size_t)cc * 128 + g * 16;

  f32x4 acc[4][4]{};
  bf16x8 b0[8], b1[8];
#pragma unroll
  for (int r = 0; r < 4; ++r) gload16(aSb[r], aD0[r]);
  LOADB_ASM(b0, bB);

  for (int s2 = 0; s2 < 32; ++s2) {
    // ---- even step s=2*s2: compute buf0/b0, prefetch s+1 -> buf1/b1 ----
    {
#pragma unroll
      for (int r = 0; r < 4; ++r) gload16(aSb[r] + (size_t)(2 * s2 + 1) * 128, aD1[r]);
      LOADB_ASM(b1, bB + 8192);
      asm volatile("s_waitcnt vmcnt(12)" ::: "memory");
      __builtin_amdgcn_sched_barrier(0);
      __builtin_amdgcn_s_barrier();
      __builtin_amdgcn_sched_barrier(0);
      COMPUTE(As2, b0);
      asm volatile("s_waitcnt lgkmcnt(0)" ::: "memory");
      __builtin_amdgcn_s_barrier();
    }
    // ---- odd step s=2*s2+1: compute buf1/b1, prefetch s+2 -> buf0/b0 ----
    {
      if (s2 < 31) {
#pragma unroll
        for (int r = 0; r < 4; ++r) gload16(aSb[r] + (size_t)(2 * s2 + 2) * 128, aD0[r]);
        LOADB_ASM(b0, bB + 16384);
        asm volatile("s_waitcnt vmcnt(12)" ::: "memory");
      } else {
        asm volatile("s_waitcnt vmcnt(0)" ::: "memory");
      }
      __builtin_amdgcn_sched_barrier(0);
      __builtin_amdgcn_s_barrier();
      __builtin_amdgcn_sched_barrier(0);
      COMPUTE(As2 + 16384, b1);
      asm volatile("s_waitcnt lgkmcnt(0)" ::: "memory");
      __builtin_amdgcn_s_barrier();
      bB += 16384;
    }
  }
  const float gmm = gamma[0];
  const float* xb = x + (size_t)b * CIN * HW_;
  float* ob = outp + (size_t)b * CIN * HW_;
  const int w = w0 + wn;
#pragma unroll
  for (int fm = 0; fm < 4; ++fm) {
#pragma unroll
    for (int jj = 0; jj < 4; ++jj) {
      int c = c0 + wm * 64 + fm * 16 + g * 4 + jj;
#pragma unroll
      for (int fn = 0; fn < 4; ++fn) {
        int n = w * 64 + fn * 16 + cc;
        size_t idx = (size_t)c * HW_ + n;
        ob[idx] = gmm * acc[fm][fn][jj] + xb[idx];
      }
    }
  }
}

extern "C" void kernel_launch(void* const* d_in, const int* in_sizes, int n_in,
                              void* d_out, int out_size, void* d_ws, size_t ws_size,
                              hipStream_t stream) {
  const float* x  = (const float*)d_in[0];
  const float* wq = (const float*)d_in[1];
  const float* bq = (const float*)d_in[2];
  const float* wk = (const float*)d_in[3];
  const float* bk = (const float*)d_in[4];
  const float* wv = (const float*)d_in[5];
  const float* bv = (const float*)d_in[6];
  const float* gamma = (const float*)d_in[7];
  float* outp = (float*)d_out;
  char* ws = (char*)d_ws;
  size_t off = 0;
  bf16_t* xT   = (bf16_t*)(ws + off); off += (size_t)4 * HW_ * CIN * 2;   // 16 MB
  bf16_t* Wcat = (bf16_t*)(ws + off); off += (size_t)640 * CIN * 2;       // 640 KB
  bf16_t* qfT  = (bf16_t*)(ws + off); off += (size_t)4 * HW_ * CQ * 2;    // 2 MB
  bf16_t* kfT  = (bf16_t*)(ws + off); off += (size_t)4 * HW_ * CQ * 2;    // 2 MB
  bf16_t* Vp2  = (bf16_t*)(ws + off); off += (size_t)4 * CIN * HW_ * 2;   // 16 MB
  bf16_t* Pt   = (bf16_t*)(ws + off);
  const size_t pbytes = (size_t)HW_ * HW_ * 2;                            // 32 MB / batch
  const bool full = (ws_size >= off + 4 * pbytes);

  k_wcat<<<dim3(320), dim3(256), 0, stream>>>(wq, wk, wv, Wcat);
  k_prep<<<dim3(64, 8, 4), dim3(256), 0, stream>>>(x, xT);
  k_projqk<<<dim3(32, 1, 4), dim3(256), 0, stream>>>(Wcat, xT, bq, bk, qfT, kfT);
  k_projv<<<dim3(32, 4, 4), dim3(256), 0, stream>>>(Wcat, xT, bv, Vp2);
  if (full) {
    k_energy<<<dim3(32, 64, 4), dim3(256), 0, stream>>>(qfT, kfT, Pt, 0);
    k_out<<<dim3(4, 32, 4), dim3(256), 0, stream>>>(Vp2, Pt, x, gamma, outp, 0);
  } else {
    for (int b = 0; b < 4; ++b) {
      k_energy<<<dim3(32, 64, 1), dim3(256), 0, stream>>>(qfT, kfT, Pt, b);
      k_out<<<dim3(4, 32, 1), dim3(256), 0, stream>>>(Vp2, Pt, x, gamma, outp, b);
    }
  }
}

// Round 10
// 179.313 us; speedup vs baseline: 1.3389x; 1.2953x over previous
//
#include <hip/hip_runtime.h>
#include <hip/hip_bf16.h>

// CrissCrossAttention (full spatial attention with w<->k permuted PV):
//   B=4, C=512, H=W=64, C8=64, HW=4096.
// v7 = v4 (best k_out: 97us) + bijective XCD swizzle (v6-proven: fetch 296->111MB).
//   k_wcat  : pack [wq;wk;wv] -> Wcat bf16 [640][512]
//   k_prep  : x fp32 -> xT bf16 [B][pixel][512]
//   k_projqk: GEMM rows 0..127 of Wcat -> qfT/kfT bf16 [B][pixel][64]
//   k_projv : GEMM rows 128..639, n-tile = permuted pixels -> Vp2[c][k*64+h]
//   k_energy: m-tile = (2 w x 64 h) pixels, n-tile = (k, 64 v); softmax over v;
//             writes Pt[b][w][k][v][h] via per-lane bf16x4 (4 consecutive h).
//   k_out   : out[c][(w,v)] = sum_{k,h} Vp2[c][k*64+h] * Pt[w][k][v][h];
//             both operands XOR-swizzled gload_lds, 64KB dbuf, vmcnt(8),
//             XCD swizzle co-locates 4 c-blocks per w-panel (B L2-shared).

typedef __bf16 bf16_t;
typedef __bf16 bf16x8 __attribute__((ext_vector_type(8)));
typedef __bf16 bf16x4 __attribute__((ext_vector_type(4)));
typedef float f32x4 __attribute__((ext_vector_type(4)));

#define HW_ 4096
#define CIN 512
#define CQ 64

__device__ __forceinline__ void gload16(const void* g, void* l) {
  __builtin_amdgcn_global_load_lds((const __attribute__((address_space(1))) void*)g,
                                   (__attribute__((address_space(3))) void*)l, 16, 0, 0);
}

// ---------------- weights pack ----------------
__global__ __launch_bounds__(256) void k_wcat(const float* __restrict__ wq,
                                              const float* __restrict__ wk,
                                              const float* __restrict__ wv,
                                              bf16_t* __restrict__ Wcat) {
  int idx = (blockIdx.x * 256 + threadIdx.x) * 4;
  int row = idx >> 9, c = idx & 511;
  const float* src;
  if (row < 64)       src = wq + row * 512 + c;
  else if (row < 128) src = wk + (row - 64) * 512 + c;
  else                src = wv + (row - 128) * 512 + c;
  float4 v = *(const float4*)src;
  bf16x4 o = { (bf16_t)v.x, (bf16_t)v.y, (bf16_t)v.z, (bf16_t)v.w };
  *(bf16x4*)&Wcat[idx] = o;
}

// ---------------- x transpose + bf16 ----------------
__global__ __launch_bounds__(256) void k_prep(const float* __restrict__ x, bf16_t* __restrict__ xT) {
  __shared__ float tile[64][65];
  const int b = blockIdx.z;
  const int p0 = blockIdx.x * 64, c0 = blockIdx.y * 64;
  const float* xb = x + (size_t)b * CIN * HW_;
  bf16_t* xTb = xT + (size_t)b * HW_ * CIN;
  const int tid = threadIdx.x;
  const int r = tid >> 4, q = tid & 15;
#pragma unroll
  for (int i = 0; i < 4; ++i) {
    int lr = r + 16 * i;
    float4 v = *(const float4*)&xb[(size_t)(c0 + lr) * HW_ + p0 + q * 4];
    tile[lr][q * 4 + 0] = v.x; tile[lr][q * 4 + 1] = v.y;
    tile[lr][q * 4 + 2] = v.z; tile[lr][q * 4 + 3] = v.w;
  }
  __syncthreads();
#pragma unroll
  for (int i = 0; i < 4; ++i) {
    int pr = r + 16 * i;
    bf16x4 o;
    o[0] = (bf16_t)tile[q * 4 + 0][pr];
    o[1] = (bf16_t)tile[q * 4 + 1][pr];
    o[2] = (bf16_t)tile[q * 4 + 2][pr];
    o[3] = (bf16_t)tile[q * 4 + 3][pr];
    *(bf16x4*)&xTb[(size_t)(p0 + pr) * CIN + c0 + q * 4] = o;
  }
}

// ---------------- q/k projection GEMM (Wcat rows 0..127) ----------------
__global__ __launch_bounds__(256) void k_projqk(const bf16_t* __restrict__ Wcat,
                                                const bf16_t* __restrict__ xT,
                                                const float* __restrict__ bq,
                                                const float* __restrict__ bk,
                                                bf16_t* __restrict__ qfT,
                                                bf16_t* __restrict__ kfT) {
  __shared__ bf16_t As[128][64];
  __shared__ bf16_t Bs[128][64];
  const int b = blockIdx.z;
  const int n0 = blockIdx.x * 128;
  const char* Wb = (const char*)Wcat;
  const char* Xb = (const char*)(xT + (size_t)b * HW_ * CIN);
  const int tid = threadIdx.x, wv_ = tid >> 6, lane = tid & 63;
  const int wm = wv_ >> 1, wn = wv_ & 1;
  const int g = lane >> 4, cc = lane & 15;
  f32x4 acc[4][4]{};
  for (int ks = 0; ks < 512; ks += 64) {
    if (ks) __syncthreads();
#pragma unroll
    for (int i = 0; i < 4; ++i) {
      int ch = wv_ * 4 + i;
      int rr = ch * 8 + (lane >> 3);
      int sl = (lane & 7) ^ (rr & 7);
      gload16(Wb + (size_t)rr * 1024 + ks * 2 + sl * 16, (char*)As + ch * 1024);
      gload16(Xb + (size_t)(n0 + rr) * 1024 + ks * 2 + sl * 16, (char*)Bs + ch * 1024);
    }
    __syncthreads();
#pragma unroll
    for (int k2 = 0; k2 < 2; ++k2) {
      bf16x8 a[4], bb[4];
#pragma unroll
      for (int f = 0; f < 4; ++f)
        a[f] = *(const bf16x8*)((char*)As + (wm * 64 + f * 16 + cc) * 128 + (((k2 * 4 + g) ^ (cc & 7)) * 16));
#pragma unroll
      for (int f = 0; f < 4; ++f)
        bb[f] = *(const bf16x8*)((char*)Bs + (wn * 64 + f * 16 + cc) * 128 + (((k2 * 4 + g) ^ (cc & 7)) * 16));
#pragma unroll
      for (int fm = 0; fm < 4; ++fm)
#pragma unroll
        for (int fn = 0; fn < 4; ++fn)
          acc[fm][fn] = __builtin_amdgcn_mfma_f32_16x16x32_bf16(a[fm], bb[fn], acc[fm][fn], 0, 0, 0);
    }
  }
  bf16_t* qb = qfT + (size_t)b * HW_ * CQ;
  bf16_t* kb = kfT + (size_t)b * HW_ * CQ;
#pragma unroll
  for (int fm = 0; fm < 4; ++fm) {
#pragma unroll
    for (int j = 0; j < 4; ++j) {
      int m = wm * 64 + fm * 16 + g * 4 + j;
      float bias = (m < 64) ? bq[m] : bk[m - 64];
#pragma unroll
      for (int fn = 0; fn < 4; ++fn) {
        int n = n0 + wn * 64 + fn * 16 + cc;
        float val = acc[fm][fn][j] + bias;
        if (m < 64) qb[(size_t)n * CQ + m] = (bf16_t)val;
        else        kb[(size_t)n * CQ + (m - 64)] = (bf16_t)val;
      }
    }
  }
}

// ---------------- V projection GEMM (Wcat rows 128..639, permuted pixels) ----------------
__global__ __launch_bounds__(256) void k_projv(const bf16_t* __restrict__ Wcat,
                                               const bf16_t* __restrict__ xT,
                                               const float* __restrict__ bv,
                                               bf16_t* __restrict__ Vp2) {
  __shared__ bf16_t As[128][64];
  __shared__ bf16_t Bs[128][64];
  const int b = blockIdx.z;
  const int n0 = blockIdx.x * 128, m0 = blockIdx.y * 128;
  const char* Wb = (const char*)Wcat;
  const char* Xb = (const char*)(xT + (size_t)b * HW_ * CIN);
  const int tid = threadIdx.x, wv_ = tid >> 6, lane = tid & 63;
  const int wm = wv_ >> 1, wn = wv_ & 1;
  const int g = lane >> 4, cc = lane & 15;
  f32x4 acc[4][4]{};
  for (int ks = 0; ks < 512; ks += 64) {
    if (ks) __syncthreads();
#pragma unroll
    for (int i = 0; i < 4; ++i) {
      int ch = wv_ * 4 + i;
      int rr = ch * 8 + (lane >> 3);
      int sl = (lane & 7) ^ (rr & 7);
      int pix = (rr & 63) * 64 + (blockIdx.x * 2) + (rr >> 6);  // perm(n0+rr)
      gload16(Wb + (size_t)(128 + m0 + rr) * 1024 + ks * 2 + sl * 16, (char*)As + ch * 1024);
      gload16(Xb + (size_t)pix * 1024 + ks * 2 + sl * 16, (char*)Bs + ch * 1024);
    }
    __syncthreads();
#pragma unroll
    for (int k2 = 0; k2 < 2; ++k2) {
      bf16x8 a[4], bb[4];
#pragma unroll
      for (int f = 0; f < 4; ++f)
        a[f] = *(const bf16x8*)((char*)As + (wm * 64 + f * 16 + cc) * 128 + (((k2 * 4 + g) ^ (cc & 7)) * 16));
#pragma unroll
      for (int f = 0; f < 4; ++f)
        bb[f] = *(const bf16x8*)((char*)Bs + (wn * 64 + f * 16 + cc) * 128 + (((k2 * 4 + g) ^ (cc & 7)) * 16));
#pragma unroll
      for (int fm = 0; fm < 4; ++fm)
#pragma unroll
        for (int fn = 0; fn < 4; ++fn)
          acc[fm][fn] = __builtin_amdgcn_mfma_f32_16x16x32_bf16(a[fm], bb[fn], acc[fm][fn], 0, 0, 0);
    }
  }
  bf16_t* Vb = Vp2 + (size_t)b * CIN * HW_;
#pragma unroll
  for (int fm = 0; fm < 4; ++fm) {
#pragma unroll
    for (int j = 0; j < 4; ++j) {
      int m = m0 + wm * 64 + fm * 16 + g * 4 + j;
      float bias = bv[m];
#pragma unroll
      for (int fn = 0; fn < 4; ++fn) {
        int n = n0 + wn * 64 + fn * 16 + cc;
        Vb[(size_t)m * HW_ + n] = (bf16_t)(acc[fm][fn][j] + bias);
      }
    }
  }
}

// ---------------- energy + softmax(v) -> Pt[b][w][k][v][h] ----------------
__global__ __launch_bounds__(256) void k_energy(const bf16_t* __restrict__ qfT,
                                                const bf16_t* __restrict__ kfT,
                                                bf16_t* __restrict__ Pt, int zbase) {
  __shared__ bf16_t As[128][64];
  __shared__ bf16_t Bs[64][64];
  const int b = zbase + blockIdx.z;
  const int w0 = blockIdx.x * 2, ky = blockIdx.y;
  const char* qb = (const char*)(qfT + (size_t)b * HW_ * CQ);
  const char* kb = (const char*)(kfT + (size_t)b * HW_ * CQ);
  bf16_t* Ptb = Pt + (size_t)blockIdx.z * 16777216;
  const int tid = threadIdx.x, wv_ = tid >> 6, lane = tid & 63;
  const int g = lane >> 4, cc = lane & 15;
  f32x4 acc[2][4]{};
#pragma unroll
  for (int i = 0; i < 4; ++i) {
    int ch = wv_ * 4 + i;
    int rr = ch * 8 + (lane >> 3);
    int sl = (lane & 7) ^ (rr & 7);
    int pix = (rr & 63) * 64 + w0 + (rr >> 6);
    gload16(qb + (size_t)pix * 128 + sl * 16, (char*)As + ch * 1024);
  }
#pragma unroll
  for (int i = 0; i < 2; ++i) {
    int ch = wv_ * 2 + i;
    int rr = ch * 8 + (lane >> 3);
    int sl = (lane & 7) ^ (rr & 7);
    gload16(kb + (size_t)(ky * 64 + rr) * 128 + sl * 16, (char*)Bs + ch * 1024);
  }
  __syncthreads();
#pragma unroll
  for (int k2 = 0; k2 < 2; ++k2) {
    bf16x8 a[2], bb[4];
#pragma unroll
    for (int f = 0; f < 2; ++f)
      a[f] = *(const bf16x8*)((char*)As + (wv_ * 32 + f * 16 + cc) * 128 + (((k2 * 4 + g) ^ (cc & 7)) * 16));
#pragma unroll
    for (int f = 0; f < 4; ++f)
      bb[f] = *(const bf16x8*)((char*)Bs + (f * 16 + cc) * 128 + (((k2 * 4 + g) ^ (cc & 7)) * 16));
#pragma unroll
    for (int fm = 0; fm < 2; ++fm)
#pragma unroll
      for (int fn = 0; fn < 4; ++fn)
        acc[fm][fn] = __builtin_amdgcn_mfma_f32_16x16x32_bf16(a[fm], bb[fn], acc[fm][fn], 0, 0, 0);
  }
  const int w = w0 + (wv_ >> 1);
#pragma unroll
  for (int fm = 0; fm < 2; ++fm) {
    float e[4][4], invj[4];
#pragma unroll
    for (int j = 0; j < 4; ++j) {
      float mx = fmaxf(fmaxf(acc[fm][0][j], acc[fm][1][j]), fmaxf(acc[fm][2][j], acc[fm][3][j]));
#pragma unroll
      for (int d = 1; d < 16; d <<= 1) mx = fmaxf(mx, __shfl_xor(mx, d, 64));
      float s = 0.f;
#pragma unroll
      for (int fn = 0; fn < 4; ++fn) { e[fn][j] = __expf(acc[fm][fn][j] - mx); s += e[fn][j]; }
#pragma unroll
      for (int d = 1; d < 16; d <<= 1) s += __shfl_xor(s, d, 64);
      invj[j] = __builtin_amdgcn_rcpf(s);
    }
    int h0 = (wv_ & 1) * 32 + fm * 16 + g * 4;
#pragma unroll
    for (int fn = 0; fn < 4; ++fn) {
      int v = fn * 16 + cc;
      bf16x4 pk = { (bf16_t)(e[fn][0] * invj[0]), (bf16_t)(e[fn][1] * invj[1]),
                    (bf16_t)(e[fn][2] * invj[2]), (bf16_t)(e[fn][3] * invj[3]) };
      *(bf16x4*)&Ptb[(((size_t)w * 64 + ky) * 64 + v) * 64 + h0] = pk;
    }
  }
}

// ---------------- out GEMM v7 + epilogue ----------------
// Block 128c x (2w x 64v), waves 2x2, wave tile 64x64. K-step s = k.
// A = Vp2 rows, B = Pt[w][s][v][h] 8KB; both XOR-swizzled gload_lds.
// Double-buffered 64KB, counted vmcnt(8), raw barriers.
// XCD swizzle: consecutive rsw on one XCD share B w-panels (4 c-blocks each)
// and V slices (16 w-pairs each) -> fetch ~halved (v6-measured).
__global__ __launch_bounds__(256) void k_out(const bf16_t* __restrict__ Vp2,
                                             const bf16_t* __restrict__ Pt,
                                             const float* __restrict__ x,
                                             const float* __restrict__ gamma,
                                             float* __restrict__ outp, int zbase) {
  __shared__ char Ls[65536];  // 2 x (A 16K | B 16K)
  const int lin = blockIdx.x + (blockIdx.y << 2) + (blockIdx.z << 7);
  const int nwg8 = (gridDim.z == 4) ? 64 : 16;
  const int rsw = (lin & 7) * nwg8 + (lin >> 3);
  const int c0 = (rsw & 3) * 128;
  const int w0 = ((rsw >> 2) & 31) * 2;
  const int bz = (gridDim.z == 4) ? (rsw >> 7) : 0;
  const int b = zbase + bz;
  const char* Vb = (const char*)(Vp2 + (size_t)b * CIN * HW_);
  const char* Pb = (const char*)(Pt + (size_t)bz * 16777216);
  const int tid = threadIdx.x, wv_ = tid >> 6, lane = tid & 63;
  const int wm = wv_ >> 1, wn = wv_ & 1;
  const int g = lane >> 4, cc = lane & 15;

  const char* aSb[4]; const char* bSb[4];
#pragma unroll
  for (int r = 0; r < 4; ++r) {
    int L = (r * 4 + wv_) * 64 + lane;
    int arow = L >> 3, asl = (L & 7) ^ (arow & 7);
    aSb[r] = Vb + (size_t)(c0 + arow) * 8192 + asl * 16;
    int ws = L >> 9, e = L & 511, v = e >> 3, bsl = (e & 7) ^ (v & 7);
    bSb[r] = Pb + (size_t)(w0 + ws) * 524288 + v * 128 + bsl * 16;
  }
  int aoff[2][4], boff[2][4];
#pragma unroll
  for (int k2 = 0; k2 < 2; ++k2) {
#pragma unroll
    for (int fm = 0; fm < 4; ++fm)
      aoff[k2][fm] = (wm * 64 + fm * 16 + cc) * 128 + (((k2 * 4 + g) ^ (cc & 7)) * 16);
#pragma unroll
    for (int fn = 0; fn < 4; ++fn)
      boff[k2][fn] = 16384 + wn * 8192 + (fn * 16 + cc) * 128 + (((k2 * 4 + g) ^ (cc & 7)) * 16);
  }

  f32x4 acc[4][4]{};
  // prologue: stage s=0 into buf0
  {
    char* base = Ls;
#pragma unroll
    for (int r = 0; r < 4; ++r) gload16(aSb[r], base + (r * 4 + wv_) * 1024);
#pragma unroll
    for (int r = 0; r < 4; ++r) gload16(bSb[r], base + 16384 + (r * 4 + wv_) * 1024);
  }
  for (int s = 0; s < 64; ++s) {
    if (s < 63) {
      char* base = Ls + ((s + 1) & 1) * 32768;
#pragma unroll
      for (int r = 0; r < 4; ++r) gload16(aSb[r] + (size_t)(s + 1) * 128, base + (r * 4 + wv_) * 1024);
#pragma unroll
      for (int r = 0; r < 4; ++r) gload16(bSb[r] + (size_t)(s + 1) * 8192, base + 16384 + (r * 4 + wv_) * 1024);
      asm volatile("s_waitcnt vmcnt(8)" ::: "memory");
    } else {
      asm volatile("s_waitcnt vmcnt(0)" ::: "memory");
    }
    __builtin_amdgcn_s_barrier();
    const char* base = Ls + (s & 1) * 32768;
#pragma unroll
    for (int k2 = 0; k2 < 2; ++k2) {
      bf16x8 a[4], bb[4];
#pragma unroll
      for (int fm = 0; fm < 4; ++fm) a[fm] = *(const bf16x8*)(base + aoff[k2][fm]);
#pragma unroll
      for (int fn = 0; fn < 4; ++fn) bb[fn] = *(const bf16x8*)(base + boff[k2][fn]);
#pragma unroll
      for (int fm = 0; fm < 4; ++fm)
#pragma unroll
        for (int fn = 0; fn < 4; ++fn)
          acc[fm][fn] = __builtin_amdgcn_mfma_f32_16x16x32_bf16(a[fm], bb[fn], acc[fm][fn], 0, 0, 0);
    }
    asm volatile("s_waitcnt lgkmcnt(0)" ::: "memory");
    __builtin_amdgcn_s_barrier();
  }
  const float gmm = gamma[0];
  const float* xb = x + (size_t)b * CIN * HW_;
  float* ob = outp + (size_t)b * CIN * HW_;
  const int w = w0 + wn;
#pragma unroll
  for (int fm = 0; fm < 4; ++fm) {
#pragma unroll
    for (int jj = 0; jj < 4; ++jj) {
      int c = c0 + wm * 64 + fm * 16 + g * 4 + jj;
#pragma unroll
      for (int fn = 0; fn < 4; ++fn) {
        int n = w * 64 + fn * 16 + cc;
        size_t idx = (size_t)c * HW_ + n;
        ob[idx] = gmm * acc[fm][fn][jj] + xb[idx];
      }
    }
  }
}

extern "C" void kernel_launch(void* const* d_in, const int* in_sizes, int n_in,
                              void* d_out, int out_size, void* d_ws, size_t ws_size,
                              hipStream_t stream) {
  const float* x  = (const float*)d_in[0];
  const float* wq = (const float*)d_in[1];
  const float* bq = (const float*)d_in[2];
  const float* wk = (const float*)d_in[3];
  const float* bk = (const float*)d_in[4];
  const float* wv = (const float*)d_in[5];
  const float* bv = (const float*)d_in[6];
  const float* gamma = (const float*)d_in[7];
  float* outp = (float*)d_out;
  char* ws = (char*)d_ws;
  size_t off = 0;
  bf16_t* xT   = (bf16_t*)(ws + off); off += (size_t)4 * HW_ * CIN * 2;   // 16 MB
  bf16_t* Wcat = (bf16_t*)(ws + off); off += (size_t)640 * CIN * 2;       // 640 KB
  bf16_t* qfT  = (bf16_t*)(ws + off); off += (size_t)4 * HW_ * CQ * 2;    // 2 MB
  bf16_t* kfT  = (bf16_t*)(ws + off); off += (size_t)4 * HW_ * CQ * 2;    // 2 MB
  bf16_t* Vp2  = (bf16_t*)(ws + off); off += (size_t)4 * CIN * HW_ * 2;   // 16 MB
  bf16_t* Pt   = (bf16_t*)(ws + off);
  const size_t pbytes = (size_t)HW_ * HW_ * 2;                            // 32 MB / batch
  const bool full = (ws_size >= off + 4 * pbytes);

  k_wcat<<<dim3(320), dim3(256), 0, stream>>>(wq, wk, wv, Wcat);
  k_prep<<<dim3(64, 8, 4), dim3(256), 0, stream>>>(x, xT);
  k_projqk<<<dim3(32, 1, 4), dim3(256), 0, stream>>>(Wcat, xT, bq, bk, qfT, kfT);
  k_projv<<<dim3(32, 4, 4), dim3(256), 0, stream>>>(Wcat, xT, bv, Vp2);
  if (full) {
    k_energy<<<dim3(32, 64, 4), dim3(256), 0, stream>>>(qfT, kfT, Pt, 0);
    k_out<<<dim3(4, 32, 4), dim3(256), 0, stream>>>(Vp2, Pt, x, gamma, outp, 0);
  } else {
    for (int b = 0; b < 4; ++b) {
      k_energy<<<dim3(32, 64, 1), dim3(256), 0, stream>>>(qfT, kfT, Pt, b);
      k_out<<<dim3(4, 32, 1), dim3(256), 0, stream>>>(Vp2, Pt, x, gamma, outp, b);
    }
  }
}